// Round 6
// baseline (134.713 us; speedup 1.0000x reference)
//
#include <hip/hip_runtime.h>

#define NQ   6
#define DIM  64      // 2^NQ
#define NMOD 32
#define NCL  32
#define BATCH 2048
#define NCLS 150
#define KF   192     // NMOD*NQ

// ws layout:
//   UB   : NMOD * 4 planes * 4096 ushorts = 1 MiB  (frag-ready bf16 U planes)
//          plane order: 0=re_hi 1=re_lo 2=im_hi 3=im_lo
//   outs : BATCH*KF floats at float-offset 262144
#define OFF_OUTS  262144

typedef short bf16x8 __attribute__((ext_vector_type(8)));
typedef float f32x16 __attribute__((ext_vector_type(16)));

// ---------------------------------------------------------------------------
// k_prep: build U_p (one wave per (p,col); lane = row i), then scatter-store
// split-bf16 planes in A-fragment-ready order:
//   frag id = (mi=i>>5)*4 + (kstep=j>>4); lane_a = (i&31) | ((j>>3)&1)<<5;
//   e = j&7  ->  ushort index F = fragid*512 + lane_a*8 + e
__global__ __launch_bounds__(256) void k_prep(const float* __restrict__ qw,
                                              unsigned short* __restrict__ UB) {
    __shared__ float2 csl[NCL * NQ];
    int tid = threadIdx.x;
    int lane = tid & 63;
    int w = tid >> 6;
    int p = blockIdx.x >> 4;
    int col = ((blockIdx.x & 15) << 2) + w;

    if (tid < NCL * NQ) {
        float s, c;
        __sincosf(0.5f * qw[p * NCL * NQ + tid], &s, &c);
        csl[tid] = make_float2(c, s);
    }
    __syncthreads();

    // fixed CNOT-ring permutation (verified R4/R5)
    int dst = lane;
#pragma unroll
    for (int q = 0; q < NQ; ++q) {
        int cm = 1 << (5 - q), tm = 1 << (5 - ((q + 1) % 6));
        dst ^= (dst & cm) ? tm : 0;
    }
    int dst_b = dst << 2;

    float re = (lane == col) ? 1.f : 0.f;
    float im = 0.f;
    for (int layer = 0; layer < NCL; ++layer) {
#pragma unroll
        for (int q = 0; q < NQ; ++q) {
            float2 cs = csl[layer * NQ + q];
            int mask = 1 << (5 - q);
            float pre = __shfl_xor(re, mask, 64);
            float pim = __shfl_xor(im, mask, 64);
            float nre = fmaf(cs.x, re, cs.y * pim);
            float nim = fmaf(cs.x, im, -cs.y * pre);
            re = nre;
            im = nim;
        }
        re = __int_as_float(__builtin_amdgcn_ds_permute(dst_b, __float_as_int(re)));
        im = __int_as_float(__builtin_amdgcn_ds_permute(dst_b, __float_as_int(im)));
    }

    // split-bf16 (truncation split: lo = x - trunc_bf16(x))
    int F = (((lane >> 5) * 4 + (col >> 4)) << 9)
          + (((lane & 31) | (((col >> 3) & 1) << 5)) << 3) + (col & 7);
    unsigned short* base = UB + (size_t)p * 4 * 4096;
    unsigned int rb = __float_as_uint(re);
    float rhf = __uint_as_float(rb & 0xFFFF0000u);
    unsigned int rlb = __float_as_uint(re - rhf);
    unsigned int ib = __float_as_uint(im);
    float ihf = __uint_as_float(ib & 0xFFFF0000u);
    unsigned int ilb = __float_as_uint(im - ihf);
    base[0 * 4096 + F] = (unsigned short)(rb >> 16);
    base[1 * 4096 + F] = (unsigned short)(rlb >> 16);
    base[2 * 4096 + F] = (unsigned short)(ib >> 16);
    base[3 * 4096 + F] = (unsigned short)(ilb >> 16);
}

// ---------------------------------------------------------------------------
// k_fused: angles GEMM + sincos + psi + split-bf16 MFMA matvec + measurement.
// One block per (p, 64-batch tile); wave w: mi = w>>1 (rows), nb = w&1 (cols).
union SharedU {
    struct { float A[64 * 65]; } s01;
    struct { unsigned short hi[64 * 72]; unsigned short lo[64 * 72]; } s23;  // 144 B row stride
};

__global__ __launch_bounds__(256, 4) void k_fused(const float* __restrict__ features,
                                                  const float* __restrict__ Wp,
                                                  const float* __restrict__ bp,
                                                  const unsigned short* __restrict__ UB,
                                                  float* __restrict__ outs) {
    __shared__ __align__(16) SharedU sh;
    __shared__ float camps_l[64 * 13];
    __shared__ float zacc[4][6][32];

    int tid = threadIdx.x;
    int lane = tid & 63;
    int w = tid >> 6;
    int p = blockIdx.x & 31;
    int btile = blockIdx.x >> 5;

    // ---- stage 0: feature tile into LDS ----
    {
        int l = tid >> 2;
        int quarter = tid & 3;
        const float* src = features + (size_t)(btile * 64 + l) * 2048 + p * 64
                         + quarter * 16;
        float4 v0 = *(const float4*)(src + 0);
        float4 v1 = *(const float4*)(src + 4);
        float4 v2 = *(const float4*)(src + 8);
        float4 v3 = *(const float4*)(src + 12);
        int d0 = quarter * 16;
        float tmp[16] = {v0.x,v0.y,v0.z,v0.w, v1.x,v1.y,v1.z,v1.w,
                         v2.x,v2.y,v2.z,v2.w, v3.x,v3.y,v3.z,v3.w};
#pragma unroll
        for (int j = 0; j < 16; ++j) sh.s01.A[(d0 + j) * 65 + l] = tmp[j];
    }
    __syncthreads();

    // ---- stage 1: angles = A @ Wp^T + bp (Wp via wave-uniform scalar loads) ----
    {
        int l = tid & 63;
        int q0 = tid >> 6;
        float acc0 = 0.f, acc1 = 0.f;
        bool two = (q0 < 2);
        int q1 = q0 + 4;
        const float* w0 = Wp + q0 * 64;
        const float* w1 = Wp + q1 * 64;
#pragma unroll
        for (int d = 0; d < 64; ++d) {
            float a = sh.s01.A[d * 65 + l];
            acc0 = fmaf(a, w0[d], acc0);
            if (two) acc1 = fmaf(a, w1[d], acc1);
        }
        float s, c;
        __sincosf(0.5f * (acc0 + bp[q0]), &s, &c);
        camps_l[l * 13 + 2 * q0 + 0] = c;
        camps_l[l * 13 + 2 * q0 + 1] = s;
        if (two) {
            __sincosf(0.5f * (acc1 + bp[q1]), &s, &c);
            camps_l[l * 13 + 2 * q1 + 0] = c;
            camps_l[l * 13 + 2 * q1 + 1] = s;
        }
    }
    __syncthreads();   // also fences ldsA reads before psi overlay writes

    // ---- stage 2: psi slice -> split-bf16 planes in LDS ----
    // v bit (4-q) <-> qubit q (q=0..4); j = 2v + b0, b0 <-> qubit5.
    // This wave needs only v in [8w, 8w+8): prefix over qubits 0,1 (w bits),
    // then a 3-level doubling over qubits 2,3,4.
    {
        float ca[12];
#pragma unroll
        for (int j = 0; j < 12; ++j) ca[j] = camps_l[lane * 13 + j];

        float pref = ((w & 2) ? ca[1] : ca[0]) * ((w & 1) ? ca[3] : ca[2]);
        float arr[8];
        arr[0] = pref * ca[4];                 // qubit2 cos
        arr[4] = pref * ca[5];                 // qubit2 sin
        arr[2] = arr[0] * ca[7]; arr[6] = arr[4] * ca[7];   // qubit3 sin
        arr[0] = arr[0] * ca[6]; arr[4] = arr[4] * ca[6];   // qubit3 cos
        arr[1] = arr[0] * ca[9]; arr[3] = arr[2] * ca[9];   // qubit4 sin
        arr[5] = arr[4] * ca[9]; arr[7] = arr[6] * ca[9];
        arr[0] *= ca[8]; arr[2] *= ca[8]; arr[4] *= ca[8]; arr[6] *= ca[8];
        float c5 = ca[10], s5 = ca[11];

        unsigned int* pHi = (unsigned int*)sh.s23.hi;
        unsigned int* pLo = (unsigned int*)sh.s23.lo;
#pragma unroll
        for (int u = 0; u < 8; ++u) {
            int v = w * 8 + u;
            float f0 = arr[u] * c5, f1 = arr[u] * s5;   // j=2v, 2v+1
            unsigned int b0 = __float_as_uint(f0), b1 = __float_as_uint(f1);
            unsigned int hi = (b0 >> 16) | (b1 & 0xFFFF0000u);
            float f0h = __uint_as_float(b0 & 0xFFFF0000u);
            float f1h = __uint_as_float(b1 & 0xFFFF0000u);
            unsigned int l0 = __float_as_uint(f0 - f0h);
            unsigned int l1 = __float_as_uint(f1 - f1h);
            unsigned int lo = (l0 >> 16) | (l1 & 0xFFFF0000u);
            pHi[lane * 36 + v] = hi;
            pLo[lane * 36 + v] = lo;
        }
    }
    __syncthreads();

    // ---- stage 3: split-bf16 MFMA: C[i][b] = U[i][j] psi[j][b] ----
    int mi = w >> 1, nb = w & 1;
    int h = lane >> 5;
    int bloc = nb * 32 + (lane & 31);
    f32x16 accR, accI;
#pragma unroll
    for (int r = 0; r < 16; ++r) { accR[r] = 0.f; accI[r] = 0.f; }

    const unsigned short* Af = UB + (size_t)p * 16384 + ((mi * 4) << 9) + (lane << 3);
#pragma unroll
    for (int t = 0; t < 4; ++t) {
        const unsigned short* fp = Af + (t << 9);
        bf16x8 aRH = *(const bf16x8*)(fp + 0 * 4096);
        bf16x8 aRL = *(const bf16x8*)(fp + 1 * 4096);
        bf16x8 aIH = *(const bf16x8*)(fp + 2 * 4096);
        bf16x8 aIL = *(const bf16x8*)(fp + 3 * 4096);
        const unsigned short* bh = sh.s23.hi + bloc * 72 + t * 16 + 8 * h;
        const unsigned short* bl = sh.s23.lo + bloc * 72 + t * 16 + 8 * h;
        bf16x8 bH = *(const bf16x8*)bh;
        bf16x8 bL = *(const bf16x8*)bl;
        accR = __builtin_amdgcn_mfma_f32_32x32x16_bf16(aRH, bH, accR, 0, 0, 0);
        accR = __builtin_amdgcn_mfma_f32_32x32x16_bf16(aRH, bL, accR, 0, 0, 0);
        accR = __builtin_amdgcn_mfma_f32_32x32x16_bf16(aRL, bH, accR, 0, 0, 0);
        accI = __builtin_amdgcn_mfma_f32_32x32x16_bf16(aIH, bH, accI, 0, 0, 0);
        accI = __builtin_amdgcn_mfma_f32_32x32x16_bf16(aIH, bL, accI, 0, 0, 0);
        accI = __builtin_amdgcn_mfma_f32_32x32x16_bf16(aIL, bH, accI, 0, 0, 0);
    }

    // ---- measurement: row m = (reg&3) + 8*(reg>>2) + 4*h, i = mi*32 + m ----
    {
        float pr[16];
#pragma unroll
        for (int r = 0; r < 16; ++r)
            pr[r] = fmaf(accR[r], accR[r], accI[r] * accI[r]);

        float zA = 0.f, z1 = 0.f, z2 = 0.f, z4 = 0.f, z5 = 0.f;
#pragma unroll
        for (int g = 0; g < 4; ++g) {
            float r0 = pr[4 * g], r1 = pr[4 * g + 1], r2 = pr[4 * g + 2], r3 = pr[4 * g + 3];
            float a  = (r0 + r1) + (r2 + r3);
            float s5 = (r0 - r1) + (r2 - r3);
            float s4 = (r0 + r1) - (r2 + r3);
            zA += a;
            z2 += (g & 1) ? -a : a;
            z1 += (g & 2) ? -a : a;
            z5 += s5;
            z4 += s4;
        }
        float tA = __shfl_xor(zA, 32, 64);
        float z3 = h ? (tA - zA) : (zA - tA);
        zA += tA;
        z1 += __shfl_xor(z1, 32, 64);
        z2 += __shfl_xor(z2, 32, 64);
        z4 += __shfl_xor(z4, 32, 64);
        z5 += __shfl_xor(z5, 32, 64);

        if (lane < 32) {
            zacc[w][0][lane] = zA;
            zacc[w][1][lane] = z1;
            zacc[w][2][lane] = z2;
            zacc[w][3][lane] = z3;
            zacc[w][4][lane] = z4;
            zacc[w][5][lane] = z5;
        }
    }
    __syncthreads();

    if (tid < 64) {
        int nb2 = tid >> 5, c = tid & 31;
        int wA = nb2, wB = 2 + nb2;          // w = (mi<<1)|nb
        float z0 = zacc[wA][0][c] - zacc[wB][0][c];
        float o1 = zacc[wA][1][c] + zacc[wB][1][c];
        float o2 = zacc[wA][2][c] + zacc[wB][2][c];
        float o3 = zacc[wA][3][c] + zacc[wB][3][c];
        float o4 = zacc[wA][4][c] + zacc[wB][4][c];
        float o5 = zacc[wA][5][c] + zacc[wB][5][c];
        float* o = outs + (size_t)(btile * 64 + tid) * KF + p * NQ;
        o[0] = z0; o[1] = o1; o[2] = o2; o[3] = o3; o[4] = o4; o[5] = o5;
    }
}

// ---------------------------------------------------------------------------
// k_final: out = outs @ Wf^T + bf.
__global__ __launch_bounds__(256) void k_final(const float* __restrict__ outs,
                                               const float* __restrict__ Wf,
                                               const float* __restrict__ bf,
                                               float* __restrict__ out) {
    int tid = threadIdx.x;
    int b = blockIdx.x * 64 + (tid & 63);
    int c = blockIdx.y * 4 + (tid >> 6);
    if (c >= NCLS) return;
    float acc = bf[c];
    const float* orow = outs + (size_t)b * KF;
    const float* wrow = Wf + (size_t)c * KF;
#pragma unroll
    for (int k = 0; k < KF; k += 4) {
        float4 o = *(const float4*)&orow[k];
        float4 wv = *(const float4*)&wrow[k];
        acc = fmaf(o.x, wv.x, acc);
        acc = fmaf(o.y, wv.y, acc);
        acc = fmaf(o.z, wv.z, acc);
        acc = fmaf(o.w, wv.w, acc);
    }
    out[b * NCLS + c] = acc;
}

// ---------------------------------------------------------------------------
extern "C" void kernel_launch(void* const* d_in, const int* in_sizes, int n_in,
                              void* d_out, int out_size, void* d_ws, size_t ws_size,
                              hipStream_t stream) {
    const float* features = (const float*)d_in[0];
    const float* Wp       = (const float*)d_in[1];
    const float* bp       = (const float*)d_in[2];
    const float* qw       = (const float*)d_in[3];
    const float* Wf       = (const float*)d_in[4];
    const float* bf       = (const float*)d_in[5];
    float* out = (float*)d_out;
    float* ws  = (float*)d_ws;

    unsigned short* UB = (unsigned short*)ws;          // 1 MiB
    float* outsb = ws + OFF_OUTS;

    k_prep<<<NMOD * 16, 256, 0, stream>>>(qw, UB);
    k_fused<<<NMOD * (BATCH / 64), 256, 0, stream>>>(features, Wp, bp, UB, outsb);
    k_final<<<dim3(BATCH / 64, (NCLS + 3) / 4), 256, 0, stream>>>(outsb, Wf, bf, out);
}

// Round 8
// 133.304 us; speedup vs baseline: 1.0106x; 1.0106x over previous
//
#include <hip/hip_runtime.h>

#define NQ   6
#define DIM  64      // 2^NQ
#define NMOD 32
#define NCL  32
#define BATCH 2048
#define NCLS 150
#define KF   192     // NMOD*NQ

// ws layout:
//   UB   : NMOD * 4 planes * 4096 ushorts = 1 MiB  (frag-ready bf16 U planes)
//          plane order: 0=re_hi 1=re_lo 2=im_hi 3=im_lo
//   outs : BATCH*KF floats at float-offset 262144
#define OFF_OUTS  262144

typedef short bf16x8 __attribute__((ext_vector_type(8)));
typedef float f32x16 __attribute__((ext_vector_type(16)));

// ---------------------------------------------------------------------------
// k_prep: build U_p (one wave per (p,col); lane = row i), then scatter-store
// split-bf16 planes in A-fragment-ready order:
//   frag id = (mi=i>>5)*4 + (kstep=j>>4); lane_a = (i&31) | ((j>>3)&1)<<5;
//   e = j&7  ->  ushort index F = fragid*512 + lane_a*8 + e
__global__ __launch_bounds__(256) void k_prep(const float* __restrict__ qw,
                                              unsigned short* __restrict__ UB) {
    __shared__ float2 csl[NCL * NQ];
    int tid = threadIdx.x;
    int lane = tid & 63;
    int w = tid >> 6;
    int p = blockIdx.x >> 4;
    int col = ((blockIdx.x & 15) << 2) + w;

    if (tid < NCL * NQ) {
        float s, c;
        __sincosf(0.5f * qw[p * NCL * NQ + tid], &s, &c);
        csl[tid] = make_float2(c, s);
    }
    __syncthreads();

    // fixed CNOT-ring permutation (verified R4/R5)
    int dst = lane;
#pragma unroll
    for (int q = 0; q < NQ; ++q) {
        int cm = 1 << (5 - q), tm = 1 << (5 - ((q + 1) % 6));
        dst ^= (dst & cm) ? tm : 0;
    }
    int dst_b = dst << 2;

    float re = (lane == col) ? 1.f : 0.f;
    float im = 0.f;
    for (int layer = 0; layer < NCL; ++layer) {
#pragma unroll
        for (int q = 0; q < NQ; ++q) {
            float2 cs = csl[layer * NQ + q];
            int mask = 1 << (5 - q);
            float pre = __shfl_xor(re, mask, 64);
            float pim = __shfl_xor(im, mask, 64);
            float nre = fmaf(cs.x, re, cs.y * pim);
            float nim = fmaf(cs.x, im, -cs.y * pre);
            re = nre;
            im = nim;
        }
        re = __int_as_float(__builtin_amdgcn_ds_permute(dst_b, __float_as_int(re)));
        im = __int_as_float(__builtin_amdgcn_ds_permute(dst_b, __float_as_int(im)));
    }

    // split-bf16 (truncation split: lo = x - trunc_bf16(x))
    int F = (((lane >> 5) * 4 + (col >> 4)) << 9)
          + (((lane & 31) | (((col >> 3) & 1) << 5)) << 3) + (col & 7);
    unsigned short* base = UB + (size_t)p * 4 * 4096;
    unsigned int rb = __float_as_uint(re);
    float rhf = __uint_as_float(rb & 0xFFFF0000u);
    unsigned int rlb = __float_as_uint(re - rhf);
    unsigned int ib = __float_as_uint(im);
    float ihf = __uint_as_float(ib & 0xFFFF0000u);
    unsigned int ilb = __float_as_uint(im - ihf);
    base[0 * 4096 + F] = (unsigned short)(rb >> 16);
    base[1 * 4096 + F] = (unsigned short)(rlb >> 16);
    base[2 * 4096 + F] = (unsigned short)(ib >> 16);
    base[3 * 4096 + F] = (unsigned short)(ilb >> 16);
}

// ---------------------------------------------------------------------------
// k_fused: angles GEMM + sincos + psi + split-bf16 MFMA matvec + measurement.
// One block per (p, 64-batch tile); wave w: mi = w>>1 (rows), nb = w&1 (cols).
union SharedU {
    struct { float A[64 * 65]; } s01;
    struct { unsigned short hi[64 * 72]; unsigned short lo[64 * 72]; } s23;  // 144 B row stride
};

__global__ __launch_bounds__(256, 4) void k_fused(const float* __restrict__ features,
                                                  const float* __restrict__ Wp,
                                                  const float* __restrict__ bp,
                                                  const unsigned short* __restrict__ UB,
                                                  float* __restrict__ outs) {
    __shared__ __align__(16) SharedU sh;
    __shared__ float camps_l[64 * 13];
    __shared__ float zacc[4][6][32];

    int tid = threadIdx.x;
    int lane = tid & 63;
    int w = tid >> 6;
    int p = blockIdx.x & 31;
    int btile = blockIdx.x >> 5;

    // ---- stage 0: feature tile into LDS ----
    {
        int l = tid >> 2;
        int quarter = tid & 3;
        const float* src = features + (size_t)(btile * 64 + l) * 2048 + p * 64
                         + quarter * 16;
        float4 v0 = *(const float4*)(src + 0);
        float4 v1 = *(const float4*)(src + 4);
        float4 v2 = *(const float4*)(src + 8);
        float4 v3 = *(const float4*)(src + 12);
        int d0 = quarter * 16;
        float tmp[16] = {v0.x,v0.y,v0.z,v0.w, v1.x,v1.y,v1.z,v1.w,
                         v2.x,v2.y,v2.z,v2.w, v3.x,v3.y,v3.z,v3.w};
#pragma unroll
        for (int j = 0; j < 16; ++j) sh.s01.A[(d0 + j) * 65 + l] = tmp[j];
    }
    __syncthreads();

    // ---- stage 1: angles = A @ Wp^T + bp (Wp via wave-uniform scalar loads) ----
    {
        int l = tid & 63;
        int q0 = tid >> 6;
        float acc0 = 0.f, acc1 = 0.f;
        bool two = (q0 < 2);
        int q1 = q0 + 4;
        const float* w0 = Wp + q0 * 64;
        const float* w1 = Wp + q1 * 64;
#pragma unroll
        for (int d = 0; d < 64; ++d) {
            float a = sh.s01.A[d * 65 + l];
            acc0 = fmaf(a, w0[d], acc0);
            if (two) acc1 = fmaf(a, w1[d], acc1);
        }
        float s, c;
        __sincosf(0.5f * (acc0 + bp[q0]), &s, &c);
        camps_l[l * 13 + 2 * q0 + 0] = c;
        camps_l[l * 13 + 2 * q0 + 1] = s;
        if (two) {
            __sincosf(0.5f * (acc1 + bp[q1]), &s, &c);
            camps_l[l * 13 + 2 * q1 + 0] = c;
            camps_l[l * 13 + 2 * q1 + 1] = s;
        }
    }
    __syncthreads();   // also fences ldsA reads before psi overlay writes

    // ---- stage 2: psi slice -> split-bf16 planes in LDS ----
    // v bit (4-q) <-> qubit q (q=0..4); j = 2v + b0, b0 <-> qubit5.
    // This wave needs only v in [8w, 8w+8): prefix over qubits 0,1 (w bits),
    // then a 3-level doubling over qubits 2,3,4.
    {
        float ca[12];
#pragma unroll
        for (int j = 0; j < 12; ++j) ca[j] = camps_l[lane * 13 + j];

        float pref = ((w & 2) ? ca[1] : ca[0]) * ((w & 1) ? ca[3] : ca[2]);
        float arr[8];
        arr[0] = pref * ca[4];
        arr[4] = pref * ca[5];
        arr[2] = arr[0] * ca[7]; arr[6] = arr[4] * ca[7];
        arr[0] = arr[0] * ca[6]; arr[4] = arr[4] * ca[6];
        arr[1] = arr[0] * ca[9]; arr[3] = arr[2] * ca[9];
        arr[5] = arr[4] * ca[9]; arr[7] = arr[6] * ca[9];
        arr[0] *= ca[8]; arr[2] *= ca[8]; arr[4] *= ca[8]; arr[6] *= ca[8];
        float c5 = ca[10], s5 = ca[11];

        unsigned int* pHi = (unsigned int*)sh.s23.hi;
        unsigned int* pLo = (unsigned int*)sh.s23.lo;
#pragma unroll
        for (int u = 0; u < 8; ++u) {
            int v = w * 8 + u;
            float f0 = arr[u] * c5, f1 = arr[u] * s5;   // j=2v, 2v+1
            unsigned int b0 = __float_as_uint(f0), b1 = __float_as_uint(f1);
            unsigned int hi = (b0 >> 16) | (b1 & 0xFFFF0000u);
            float f0h = __uint_as_float(b0 & 0xFFFF0000u);
            float f1h = __uint_as_float(b1 & 0xFFFF0000u);
            unsigned int l0 = __float_as_uint(f0 - f0h);
            unsigned int l1 = __float_as_uint(f1 - f1h);
            unsigned int lo = (l0 >> 16) | (l1 & 0xFFFF0000u);
            pHi[lane * 36 + v] = hi;
            pLo[lane * 36 + v] = lo;
        }
    }
    __syncthreads();

    // ---- stage 3: split-bf16 MFMA: C[i][b] = U[i][j] psi[j][b] ----
    int mi = w >> 1, nb = w & 1;
    int h = lane >> 5;
    int bloc = nb * 32 + (lane & 31);
    f32x16 accR, accI;
#pragma unroll
    for (int r = 0; r < 16; ++r) { accR[r] = 0.f; accI[r] = 0.f; }

    const unsigned short* Af = UB + (size_t)p * 16384 + ((mi * 4) << 9) + (lane << 3);
#pragma unroll
    for (int t = 0; t < 4; ++t) {
        const unsigned short* fp = Af + (t << 9);
        bf16x8 aRH = *(const bf16x8*)(fp + 0 * 4096);
        bf16x8 aRL = *(const bf16x8*)(fp + 1 * 4096);
        bf16x8 aIH = *(const bf16x8*)(fp + 2 * 4096);
        bf16x8 aIL = *(const bf16x8*)(fp + 3 * 4096);
        const unsigned short* bh = sh.s23.hi + bloc * 72 + t * 16 + 8 * h;
        const unsigned short* bl = sh.s23.lo + bloc * 72 + t * 16 + 8 * h;
        bf16x8 bH = *(const bf16x8*)bh;
        bf16x8 bL = *(const bf16x8*)bl;
        accR = __builtin_amdgcn_mfma_f32_32x32x16_bf16(aRH, bH, accR, 0, 0, 0);
        accR = __builtin_amdgcn_mfma_f32_32x32x16_bf16(aRH, bL, accR, 0, 0, 0);
        accR = __builtin_amdgcn_mfma_f32_32x32x16_bf16(aRL, bH, accR, 0, 0, 0);
        accI = __builtin_amdgcn_mfma_f32_32x32x16_bf16(aIH, bH, accI, 0, 0, 0);
        accI = __builtin_amdgcn_mfma_f32_32x32x16_bf16(aIH, bL, accI, 0, 0, 0);
        accI = __builtin_amdgcn_mfma_f32_32x32x16_bf16(aIL, bH, accI, 0, 0, 0);
    }

    // ---- measurement: row m = (reg&3) + 8*(reg>>2) + 4*h, i = mi*32 + m ----
    {
        float pr[16];
#pragma unroll
        for (int r = 0; r < 16; ++r)
            pr[r] = fmaf(accR[r], accR[r], accI[r] * accI[r]);

        float zA = 0.f, z1 = 0.f, z2 = 0.f, z4 = 0.f, z5 = 0.f;
#pragma unroll
        for (int g = 0; g < 4; ++g) {
            float r0 = pr[4 * g], r1 = pr[4 * g + 1], r2 = pr[4 * g + 2], r3 = pr[4 * g + 3];
            float a  = (r0 + r1) + (r2 + r3);
            float s5 = (r0 - r1) + (r2 - r3);
            float s4 = (r0 + r1) - (r2 + r3);
            zA += a;
            z2 += (g & 1) ? -a : a;
            z1 += (g & 2) ? -a : a;
            z5 += s5;
            z4 += s4;
        }
        float tA = __shfl_xor(zA, 32, 64);
        float z3 = h ? (tA - zA) : (zA - tA);
        zA += tA;
        z1 += __shfl_xor(z1, 32, 64);
        z2 += __shfl_xor(z2, 32, 64);
        z4 += __shfl_xor(z4, 32, 64);
        z5 += __shfl_xor(z5, 32, 64);

        if (lane < 32) {
            zacc[w][0][lane] = zA;
            zacc[w][1][lane] = z1;
            zacc[w][2][lane] = z2;
            zacc[w][3][lane] = z3;
            zacc[w][4][lane] = z4;
            zacc[w][5][lane] = z5;
        }
    }
    __syncthreads();

    if (tid < 64) {
        int nb2 = tid >> 5, c = tid & 31;
        int wA = nb2, wB = 2 + nb2;          // w = (mi<<1)|nb
        float z0 = zacc[wA][0][c] - zacc[wB][0][c];
        float o1 = zacc[wA][1][c] + zacc[wB][1][c];
        float o2 = zacc[wA][2][c] + zacc[wB][2][c];
        float o3 = zacc[wA][3][c] + zacc[wB][3][c];
        float o4 = zacc[wA][4][c] + zacc[wB][4][c];
        float o5 = zacc[wA][5][c] + zacc[wB][5][c];
        float* o = outs + (size_t)(btile * 64 + tid) * KF + p * NQ;
        o[0] = z0; o[1] = o1; o[2] = o2; o[3] = o3; o[4] = o4; o[5] = o5;
    }
}

// ---------------------------------------------------------------------------
// k_final: out = outs @ Wf^T + bf.
__global__ __launch_bounds__(256) void k_final(const float* __restrict__ outs,
                                               const float* __restrict__ Wf,
                                               const float* __restrict__ bf,
                                               float* __restrict__ out) {
    int tid = threadIdx.x;
    int b = blockIdx.x * 64 + (tid & 63);
    int c = blockIdx.y * 4 + (tid >> 6);
    if (c >= NCLS) return;
    float acc = bf[c];
    const float* orow = outs + (size_t)b * KF;
    const float* wrow = Wf + (size_t)c * KF;
#pragma unroll
    for (int k = 0; k < KF; k += 4) {
        float4 o = *(const float4*)&orow[k];
        float4 wv = *(const float4*)&wrow[k];
        acc = fmaf(o.x, wv.x, acc);
        acc = fmaf(o.y, wv.y, acc);
        acc = fmaf(o.z, wv.z, acc);
        acc = fmaf(o.w, wv.w, acc);
    }
    out[b * NCLS + c] = acc;
}

// ---------------------------------------------------------------------------
extern "C" void kernel_launch(void* const* d_in, const int* in_sizes, int n_in,
                              void* d_out, int out_size, void* d_ws, size_t ws_size,
                              hipStream_t stream) {
    const float* features = (const float*)d_in[0];
    const float* Wp       = (const float*)d_in[1];
    const float* bp       = (const float*)d_in[2];
    const float* qw       = (const float*)d_in[3];
    const float* Wf       = (const float*)d_in[4];
    const float* bf       = (const float*)d_in[5];
    float* out = (float*)d_out;
    float* ws  = (float*)d_ws;

    unsigned short* UB = (unsigned short*)ws;          // 1 MiB
    float* outsb = ws + OFF_OUTS;

    k_prep<<<NMOD * 16, 256, 0, stream>>>(qw, UB);
    k_fused<<<NMOD * (BATCH / 64), 256, 0, stream>>>(features, Wp, bp, UB, outsb);
    k_final<<<dim3(BATCH / 64, (NCLS + 3) / 4), 256, 0, stream>>>(outsb, Wf, bf, out);
}